// Round 10
// baseline (3359.563 us; speedup 1.0000x reference)
//
#include <hip/hip_runtime.h>
#include <hip/hip_bf16.h>

typedef __bf16 bf16x8 __attribute__((ext_vector_type(8)));
typedef float f32x4 __attribute__((ext_vector_type(4)));
typedef unsigned long long u64;

#define TSTEPS 256
#define NB 64
#define ID 1024
#define HD 1024
#define KD 2048

// ws layout (bytes)
#define WOFF 0ull
#define VOFF 16777216ull
#define BOFF 18874368ull
#define HMOFF 18890752ull            // 257 h buffers x 65536 bf16, [t][c8][row][8] layout
#define XBOFF 52580352ull            // xb bf16 [t][row][k] = 33.5MB

#define SENT 0xFFFFFFFFu

__device__ __forceinline__ unsigned short f2b(float f) {
    unsigned int u = __float_as_uint(f);
    unsigned int r = (u + 0x7fffu + ((u >> 16) & 1u)) >> 16;
    return (unsigned short)r;
}

__device__ __forceinline__ bf16x8 as_frag(uint4 u) {
    union { uint4 u; bf16x8 v; } c; c.u = u; return c.v;
}

// coherence-point (L2-bypass) 16B load, issue only
__device__ __forceinline__ uint4 ld_b128_cp(const void* p) {
    uint4 r;
    asm volatile("global_load_dwordx4 %0, %1, off sc0 sc1" : "=v"(r) : "v"(p));
    return r;
}
// order-pinned cached 16B load
__device__ __forceinline__ uint4 ld_b128(const void* p) {
    uint4 r;
    asm volatile("global_load_dwordx4 %0, %1, off" : "=v"(r) : "v"(p));
    return r;
}

__global__ void cvt_x(const float* __restrict__ in, unsigned short* __restrict__ out) {
    size_t i = ((size_t)blockIdx.x * 256 + threadIdx.x) * 8;
    int t = (int)(i >> 16);
    int b = (int)(i >> 10) & 63;
    int k = (int)i & 1023;
    const float* src = in + ((size_t)b << 18) + ((size_t)t << 10) + k;  // x[b][t][k]
    float4 a = *(const float4*)src;
    float4 bb = *(const float4*)(src + 4);
    union { unsigned short h[8]; uint4 u; } o;
    o.h[0] = f2b(a.x); o.h[1] = f2b(a.y); o.h[2] = f2b(a.z); o.h[3] = f2b(a.w);
    o.h[4] = f2b(bb.x); o.h[5] = f2b(bb.y); o.h[6] = f2b(bb.z); o.h[7] = f2b(bb.w);
    *(uint4*)(out + i) = o.u;   // xb[t][b][k]
}

__global__ void cvt_w(const float* __restrict__ Wf, const float* __restrict__ Wi,
                      const float* __restrict__ Wo, const float* __restrict__ Wc,
                      const float* __restrict__ bf_, const float* __restrict__ bi_,
                      const float* __restrict__ bo_, const float* __restrict__ bc_,
                      unsigned short* __restrict__ Wr, float* __restrict__ bias_r) {
    int idx = blockIdx.x * 256 + threadIdx.x;   // 4096*256 total
    int np = idx >> 8;            // n' = hcol*4 + gate
    int k  = (idx & 255) * 8;
    int g = np & 3, h = np >> 2;
    const float* W = (g == 0) ? Wf : (g == 1) ? Wi : (g == 2) ? Wo : Wc;
    const float* src = W + (size_t)h * KD + k;
    float4 a = *(const float4*)src;
    float4 b = *(const float4*)(src + 4);
    union { unsigned short h[8]; uint4 u; } o;
    o.h[0] = f2b(a.x); o.h[1] = f2b(a.y); o.h[2] = f2b(a.z); o.h[3] = f2b(a.w);
    o.h[4] = f2b(b.x); o.h[5] = f2b(b.y); o.h[6] = f2b(b.z); o.h[7] = f2b(b.w);
    *(uint4*)(Wr + (size_t)np * KD + k) = o.u;
    if (k == 0) {
        const float* B = (g == 0) ? bf_ : (g == 1) ? bi_ : (g == 2) ? bo_ : bc_;
        bias_r[np] = B[h];
    }
}

__global__ void cvt_v(const float* __restrict__ V, unsigned short* __restrict__ out) {
    size_t i = ((size_t)blockIdx.x * blockDim.x + threadIdx.x) * 8;
    float4 a = *(const float4*)(V + i);
    float4 b = *(const float4*)(V + i + 4);
    union { unsigned short h[8]; uint4 u; } o;
    o.h[0] = f2b(a.x); o.h[1] = f2b(a.y); o.h[2] = f2b(a.z); o.h[3] = f2b(a.w);
    o.h[4] = f2b(b.x); o.h[5] = f2b(b.y); o.h[6] = f2b(b.z); o.h[7] = f2b(b.w);
    *(uint4*)(out + i) = o.u;
}

__global__ void init_sent(unsigned short* __restrict__ h1) {  // buffers 1..256 = sentinel
    size_t i = ((size_t)blockIdx.x * blockDim.x + threadIdx.x) * 8;
    uint4 s = {SENT, SENT, SENT, SENT};
    *(uint4*)(h1 + i) = s;
}

__device__ __forceinline__ float sigf(float x) {
    return 1.0f / (1.0f + __expf(-x));
}
__device__ __forceinline__ float tanhfast(float x) {
    return 2.0f / (1.0f + __expf(-2.0f * x)) - 1.0f;
}

__launch_bounds__(512, 1)
__global__ void lstm_core(const unsigned short* __restrict__ xb,
                          const unsigned short* __restrict__ Wr,
                          const float* __restrict__ bias_r,
                          unsigned short* __restrict__ hm,
                          const unsigned short* __restrict__ Vw,
                          const float* __restrict__ Vbias,
                          float* __restrict__ out) {
    __shared__ float gxp[8][64][20];       // projection epilogue only
    __shared__ float pbx[4][2][16][20];    // x partials, double-buffered by step parity
    __shared__ float pbh[4][16][20];       // h partials (same-wave transpose)

    const int bid  = blockIdx.x;       // 256 blocks, 16 gate-cols (4 h-cols) each
    const int tid  = threadIdx.x;      // 512 threads, 8 waves
    const int wave = tid >> 6;
    const int lane = tid & 63;
    const int lrow = lane & 15;
    const int kq   = (lane >> 4) << 3; // 0,8,16,24
    const int n0   = bid << 4;
    const int qr   = (lane >> 4) << 2;

    const bool isx = wave < 4;
    const int w4   = isx ? wave : wave - 4;   // row-tile index 0..3
    const int row0 = w4 << 4;                 // batch rows row0..row0+15
    const int crow = lane >> 2;               // cell mapping: row within tile
    const int chc  = lane & 3;                // cell mapping: hcol within block

    const unsigned short* wbase = Wr + (size_t)(n0 + lrow) * KD;
    const float4 bb = *(const float4*)&bias_r[n0 + (chc << 2)];

    // projection-epilogue mapping (tid>=256)
    const int ct   = tid - 256;
    const int ob   = (ct >> 2) & 63;
    const int lhc  = ct & 3;

    float c_reg = 0.f;
    float hlast = 0.f;

    // prologue: xpart(0) into pbx[w4][0]
    if (isx) {
        f32x4 acc = {0, 0, 0, 0};
        const unsigned short* xrow = xb + (size_t)(row0 + lrow) * 1024 + kq;
        #pragma unroll
        for (int f = 0; f < 32; ++f)
            acc = __builtin_amdgcn_mfma_f32_16x16x32_bf16(
                *(const bf16x8*)(xrow + f * 32),
                *(const bf16x8*)(wbase + f * 32 + kq), acc, 0, 0, 0);
        #pragma unroll
        for (int r = 0; r < 4; ++r) pbx[w4][0][qr + r][lrow] = acc[r];
    }
    __syncthreads();

    for (int t = 0; t < TSTEPS; ++t) {
        if (isx) {
            // prefetch xpart(t+1) into the other pbx buffer (off the h critical path)
            if (t + 1 < TSTEPS) {
                f32x4 acc = {0, 0, 0, 0};
                const unsigned short* xrow = xb + ((size_t)(t + 1) << 16)
                                                + (size_t)(row0 + lrow) * 1024 + kq;
                #pragma unroll
                for (int f = 0; f < 32; ++f)
                    acc = __builtin_amdgcn_mfma_f32_16x16x32_bf16(
                        *(const bf16x8*)(xrow + f * 32),
                        *(const bf16x8*)(wbase + f * 32 + kq), acc, 0, 0, 0);
                #pragma unroll
                for (int r = 0; r < 4; ++r) pbx[w4][(t + 1) & 1][qr + r][lrow] = acc[r];
            }
        } else {
            f32x4 acc = {0, 0, 0, 0};
            if (t > 0) {
                // h-GEMM over K=1024 in 4 quarter-pipelined chunks; sentinel in-band
                const unsigned short* hrow = hm + ((size_t)t << 16) + (size_t)(row0 + lrow) * 8;
                uint4 hq[2][8], wq[2][8];
                // q0: W (cached, pinned) then poll h until clean
                #pragma unroll
                for (int f = 0; f < 8; ++f)
                    wq[0][f] = ld_b128(wbase + 1024 + f * 32 + kq);
                int it0 = 0;
                for (;;) {
                    #pragma unroll
                    for (int f = 0; f < 8; ++f)
                        hq[0][f] = ld_b128_cp(hrow + (size_t)(f * 4 + (lane >> 4)) * 512);
                    asm volatile("s_waitcnt vmcnt(0)" ::: "memory");
                    __builtin_amdgcn_sched_barrier(0);   // rule #18
                    unsigned int bad = 0;
                    #pragma unroll
                    for (int f = 0; f < 8; ++f)
                        bad |= (hq[0][f].x == SENT) | (hq[0][f].y == SENT) |
                               (hq[0][f].z == SENT) | (hq[0][f].w == SENT);
                    if (__all(bad == 0) || ++it0 > (1 << 15)) break;
                }
                __builtin_amdgcn_sched_barrier(0);
                #pragma unroll
                for (int q = 0; q < 4; ++q) {
                    const int cur = q & 1, nxt = cur ^ 1;
                    if (q < 3) {   // issue next quarter behind this quarter's MFMAs
                        #pragma unroll
                        for (int f = 0; f < 8; ++f) {
                            wq[nxt][f] = ld_b128(wbase + 1024 + (q + 1) * 256 + f * 32 + kq);
                            hq[nxt][f] = ld_b128_cp(hrow + (size_t)((q + 1) * 32 + f * 4 + (lane >> 4)) * 512);
                        }
                    }
                    #pragma unroll
                    for (int f = 0; f < 8; ++f)
                        acc = __builtin_amdgcn_mfma_f32_16x16x32_bf16(
                            as_frag(hq[cur][f]), as_frag(wq[cur][f]), acc, 0, 0, 0);
                    if (q < 3) {
                        asm volatile("s_waitcnt vmcnt(0)" ::: "memory");
                        __builtin_amdgcn_sched_barrier(0);   // rule #18
                        int itq = 0;
                        for (;;) {
                            unsigned int bad = 0;
                            #pragma unroll
                            for (int f = 0; f < 8; ++f)
                                bad |= (hq[nxt][f].x == SENT) | (hq[nxt][f].y == SENT) |
                                       (hq[nxt][f].z == SENT) | (hq[nxt][f].w == SENT);
                            if (__all(bad == 0) || ++itq > (1 << 15)) break;
                            #pragma unroll
                            for (int f = 0; f < 8; ++f)
                                hq[nxt][f] = ld_b128_cp(hrow + (size_t)((q + 1) * 32 + f * 4 + (lane >> 4)) * 512);
                            asm volatile("s_waitcnt vmcnt(0)" ::: "memory");
                            __builtin_amdgcn_sched_barrier(0);
                        }
                        __builtin_amdgcn_sched_barrier(0);
                    }
                }
            }
            // same-wave transpose of h partials (in-order DS pipe; no barrier)
            #pragma unroll
            for (int r = 0; r < 4; ++r) pbh[w4][qr + r][lrow] = acc[r];
            asm volatile("s_waitcnt lgkmcnt(0)" ::: "memory");
            __builtin_amdgcn_sched_barrier(0);
            float4 xp = *(const float4*)&pbx[w4][t & 1][crow][chc << 2];
            float4 hp = *(const float4*)&pbh[w4][crow][chc << 2];
            float fpre = xp.x + hp.x + bb.x;
            float ipre = xp.y + hp.y + bb.y;
            float opre = xp.z + hp.z + bb.z;
            float gpre = xp.w + hp.w + bb.w;
            float fg = sigf(fpre);
            float ig = sigf(ipre);
            float og = sigf(opre);
            float gg = tanhfast(gpre);
            c_reg = fg * c_reg + ig * gg;
            float hh = og * tanhfast(c_reg);
            if (t == TSTEPS - 1) hlast = hh;

            // fire-and-forget publish: one 8B sc0sc1 store per 4 lanes
            unsigned int hb = f2b(hh);
            unsigned int p1 = __shfl_down(hb, 1);
            unsigned int p2 = __shfl_down(hb, 2);
            unsigned int p3 = __shfl_down(hb, 3);
            if (chc == 0) {
                u64 v = (u64)hb | ((u64)p1 << 16) | ((u64)p2 << 32) | ((u64)p3 << 48);
                unsigned short* dst = hm + ((size_t)(t + 1) << 16)
                                       + (size_t)(bid >> 1) * 512
                                       + (size_t)(row0 + crow) * 8 + ((bid & 1) << 2);
                asm volatile("global_store_dwordx2 %0, %1, off sc0 sc1" :: "v"(dst), "v"(v) : "memory");
            }
        }
        __syncthreads();   // pbx anti-dependency: x may now overwrite pbx[w4][t&1] next iter
    }

    // c and h outputs
    if (!isx) {
        const int rg = row0 + crow;
        const int cg = (bid << 2) + chc;
        out[(size_t)rg * HD + cg] = c_reg;
        out[65536 + (size_t)rg * HD + cg] = hlast;
    }

    // final projection: last_out = h_256 @ V^T + V_b, blocks 0..63 (N=1024)
    if (bid < 64) {
        f32x4 acc[4];
        #pragma unroll
        for (int m = 0; m < 4; ++m) acc[m] = (f32x4){0, 0, 0, 0};
        const int ko2 = (wave << 7) + kq;                       // K=1024 split 8 x 128
        const unsigned short* vp = Vw + (size_t)(n0 + lrow) * HD + ko2;
        const unsigned short* hmt = hm + ((size_t)TSTEPS << 16);
        const int c8b = ko2 >> 3;
        uint4 pw[4], pv[4][4];
        #pragma unroll
        for (int j = 0; j < 4; ++j)
            pw[j] = ld_b128(vp + j * 32);
        int it = 0;
        for (;;) {
            #pragma unroll
            for (int j = 0; j < 4; ++j)
                #pragma unroll
                for (int m = 0; m < 4; ++m)
                    pv[j][m] = ld_b128_cp(hmt + (size_t)(c8b + j * 4) * 512 + (m * 16 + lrow) * 8);
            asm volatile("s_waitcnt vmcnt(0)" ::: "memory");
            __builtin_amdgcn_sched_barrier(0);   // rule #18
            unsigned int bad = 0;
            #pragma unroll
            for (int j = 0; j < 4; ++j)
                #pragma unroll
                for (int m = 0; m < 4; ++m)
                    bad |= (pv[j][m].x == SENT) | (pv[j][m].y == SENT) |
                           (pv[j][m].z == SENT) | (pv[j][m].w == SENT);
            if (__all(bad == 0) || ++it > (1 << 14)) break;
        }
        __builtin_amdgcn_sched_barrier(0);
        #pragma unroll
        for (int j = 0; j < 4; ++j)
            #pragma unroll
            for (int m = 0; m < 4; ++m)
                acc[m] = __builtin_amdgcn_mfma_f32_16x16x32_bf16(as_frag(pv[j][m]),
                                                                 as_frag(pw[j]), acc[m], 0, 0, 0);
        #pragma unroll
        for (int m = 0; m < 4; ++m)
            #pragma unroll
            for (int r = 0; r < 4; ++r)
                gxp[wave][m * 16 + qr + r][lrow] = acc[m][r];
        __syncthreads();
        if (tid >= 256) {
            float4 vb = *(const float4*)&Vbias[n0 + (lhc << 2)];
            float4 res = vb;
            #pragma unroll
            for (int w = 0; w < 8; ++w) {
                float4 s = *(const float4*)&gxp[w][ob][lhc << 2];
                res.x += s.x; res.y += s.y; res.z += s.z; res.w += s.w;
            }
            *(float4*)&out[131072 + (size_t)ob * 1024 + n0 + (lhc << 2)] = res;
        }
    }
}

extern "C" void kernel_launch(void* const* d_in, const int* in_sizes, int n_in,
                              void* d_out, int out_size, void* d_ws, size_t ws_size,
                              hipStream_t stream) {
    const float* x   = (const float*)d_in[0];
    const float* Wf  = (const float*)d_in[1];
    const float* bf_ = (const float*)d_in[2];
    const float* Wi  = (const float*)d_in[3];
    const float* bi_ = (const float*)d_in[4];
    const float* Wc  = (const float*)d_in[5];
    const float* bc_ = (const float*)d_in[6];
    const float* Wo  = (const float*)d_in[7];
    const float* bo_ = (const float*)d_in[8];
    const float* Vw  = (const float*)d_in[9];
    const float* Vb  = (const float*)d_in[10];

    char* ws = (char*)d_ws;
    unsigned short* Wr     = (unsigned short*)(ws + WOFF);
    unsigned short* Vbf    = (unsigned short*)(ws + VOFF);
    float*          bias_r = (float*)(ws + BOFF);
    unsigned short* hm     = (unsigned short*)(ws + HMOFF);
    unsigned short* xbb    = (unsigned short*)(ws + XBOFF);
    float*          outp   = (float*)d_out;

    cvt_x <<<8192, 256, 0, stream>>>(x, xbb);
    cvt_w <<<4096, 256, 0, stream>>>(Wf, Wi, Wo, Wc, bf_, bi_, bo_, bc_, Wr, bias_r);
    cvt_v <<<512, 256, 0, stream>>>(Vw, Vbf);
    init_sent<<<8192, 256, 0, stream>>>(hm + 65536);             // slots 1..256 = sentinel

    void* args[] = {&xbb, &Wr, &bias_r, &hm, &Vbf, (void*)&Vb, &outp};
    hipLaunchCooperativeKernel((const void*)lstm_core, dim3(256), dim3(512), args, 0, stream);
}

// Round 11
// 1640.255 us; speedup vs baseline: 2.0482x; 2.0482x over previous
//
#include <hip/hip_runtime.h>
#include <hip/hip_bf16.h>

typedef __bf16 bf16x8 __attribute__((ext_vector_type(8)));
typedef float f32x4 __attribute__((ext_vector_type(4)));
typedef unsigned long long u64;

#define TSTEPS 256
#define NB 64
#define ID 1024
#define HD 1024
#define KD 2048

// ws layout (bytes)
#define WOFF 0ull
#define VOFF 16777216ull
#define BOFF 18874368ull
#define HMOFF 18890752ull            // 257 h buffers x 65536 bf16, [t][c8][row][8] layout
#define XBOFF 52580352ull            // xb bf16 [t][row][k] = 33.5MB

#define SENT 0xFFFFFFFFu

__device__ __forceinline__ unsigned short f2b(float f) {
    unsigned int u = __float_as_uint(f);
    unsigned int r = (u + 0x7fffu + ((u >> 16) & 1u)) >> 16;
    return (unsigned short)r;
}

__device__ __forceinline__ bf16x8 as_frag(uint4 u) {
    union { uint4 u; bf16x8 v; } c; c.u = u; return c.v;
}

// coherence-point (L2-bypass) 16B load, issue only
__device__ __forceinline__ uint4 ld_b128_cp(const void* p) {
    uint4 r;
    asm volatile("global_load_dwordx4 %0, %1, off sc0 sc1" : "=v"(r) : "v"(p));
    return r;
}
// order-pinned cached 16B load
__device__ __forceinline__ uint4 ld_b128(const void* p) {
    uint4 r;
    asm volatile("global_load_dwordx4 %0, %1, off" : "=v"(r) : "v"(p));
    return r;
}

__global__ void cvt_x(const float* __restrict__ in, unsigned short* __restrict__ out) {
    size_t i = ((size_t)blockIdx.x * 256 + threadIdx.x) * 8;
    int t = (int)(i >> 16);
    int b = (int)(i >> 10) & 63;
    int k = (int)i & 1023;
    const float* src = in + ((size_t)b << 18) + ((size_t)t << 10) + k;  // x[b][t][k]
    float4 a = *(const float4*)src;
    float4 bb = *(const float4*)(src + 4);
    union { unsigned short h[8]; uint4 u; } o;
    o.h[0] = f2b(a.x); o.h[1] = f2b(a.y); o.h[2] = f2b(a.z); o.h[3] = f2b(a.w);
    o.h[4] = f2b(bb.x); o.h[5] = f2b(bb.y); o.h[6] = f2b(bb.z); o.h[7] = f2b(bb.w);
    *(uint4*)(out + i) = o.u;   // xb[t][b][k]
}

__global__ void cvt_w(const float* __restrict__ Wf, const float* __restrict__ Wi,
                      const float* __restrict__ Wo, const float* __restrict__ Wc,
                      const float* __restrict__ bf_, const float* __restrict__ bi_,
                      const float* __restrict__ bo_, const float* __restrict__ bc_,
                      unsigned short* __restrict__ Wr, float* __restrict__ bias_r) {
    int idx = blockIdx.x * 256 + threadIdx.x;   // 4096*256 total
    int np = idx >> 8;            // n' = hcol*4 + gate
    int k  = (idx & 255) * 8;
    int g = np & 3, h = np >> 2;
    const float* W = (g == 0) ? Wf : (g == 1) ? Wi : (g == 2) ? Wo : Wc;
    const float* src = W + (size_t)h * KD + k;
    float4 a = *(const float4*)src;
    float4 b = *(const float4*)(src + 4);
    union { unsigned short h[8]; uint4 u; } o;
    o.h[0] = f2b(a.x); o.h[1] = f2b(a.y); o.h[2] = f2b(a.z); o.h[3] = f2b(a.w);
    o.h[4] = f2b(b.x); o.h[5] = f2b(b.y); o.h[6] = f2b(b.z); o.h[7] = f2b(b.w);
    *(uint4*)(Wr + (size_t)np * KD + k) = o.u;
    if (k == 0) {
        const float* B = (g == 0) ? bf_ : (g == 1) ? bi_ : (g == 2) ? bo_ : bc_;
        bias_r[np] = B[h];
    }
}

__global__ void cvt_v(const float* __restrict__ V, unsigned short* __restrict__ out) {
    size_t i = ((size_t)blockIdx.x * blockDim.x + threadIdx.x) * 8;
    float4 a = *(const float4*)(V + i);
    float4 b = *(const float4*)(V + i + 4);
    union { unsigned short h[8]; uint4 u; } o;
    o.h[0] = f2b(a.x); o.h[1] = f2b(a.y); o.h[2] = f2b(a.z); o.h[3] = f2b(a.w);
    o.h[4] = f2b(b.x); o.h[5] = f2b(b.y); o.h[6] = f2b(b.z); o.h[7] = f2b(b.w);
    *(uint4*)(out + i) = o.u;
}

__global__ void init_sent(unsigned short* __restrict__ h1) {  // buffers 1..256 = sentinel
    size_t i = ((size_t)blockIdx.x * blockDim.x + threadIdx.x) * 8;
    uint4 s = {SENT, SENT, SENT, SENT};
    *(uint4*)(h1 + i) = s;
}

__device__ __forceinline__ float sigf(float x) {
    return 1.0f / (1.0f + __expf(-x));
}
__device__ __forceinline__ float tanhfast(float x) {
    return 2.0f / (1.0f + __expf(-2.0f * x)) - 1.0f;
}

#define WSTRIDE 130   // k8-row stride in shorts: banks = 4*(col&7)+(lane>>4), 2-way max

__launch_bounds__(512, 1)
__global__ void lstm_core(const unsigned short* __restrict__ xb,
                          const unsigned short* __restrict__ Wr,
                          const float* __restrict__ bias_r,
                          unsigned short* __restrict__ hm,
                          const unsigned short* __restrict__ Vw,
                          const float* __restrict__ Vbias,
                          float* __restrict__ out) {
    __shared__ __align__(16) unsigned short wlds[256 * WSTRIDE];  // 66.5 KB, [k8][col][8]
    __shared__ float pbx[4][2][16][20];    // x partials, double-buffered by parity
    __shared__ float pbh[4][16][20];       // h partials (same-wave transpose)
    __shared__ float gxp[8][64][20];       // projection epilogue only

    const int bid  = blockIdx.x;       // 256 blocks, 16 gate-cols (4 h-cols) each
    const int tid  = threadIdx.x;      // 512 threads, 8 waves
    const int wave = tid >> 6;
    const int lane = tid & 63;
    const int lrow = lane & 15;
    const int kq   = (lane >> 4) << 3; // 0,8,16,24
    const int n0   = bid << 4;
    const int qr   = (lane >> 4) << 2;

    const bool isx = wave < 4;
    const int w4   = isx ? wave : wave - 4;   // row-tile index 0..3
    const int row0 = w4 << 4;                 // batch rows row0..row0+15
    const int crow = lane >> 2;               // cell: row within tile
    const int chc  = lane & 3;                // cell: hcol within block

    // W -> LDS, fragment-major (one time). 4096 fragments of 16B.
    for (int idx = tid; idx < 4096; idx += 512) {
        int k8  = idx & 255;
        int col = idx >> 8;
        uint4 v = *(const uint4*)(Wr + (size_t)(n0 + col) * KD + (size_t)k8 * 8);
        *(uint4*)&wlds[k8 * WSTRIDE + col * 8] = v;
    }
    const float4 bb = *(const float4*)&bias_r[n0 + (chc << 2)];

    // projection-epilogue mapping
    const int ct = tid - 256;
    const int ob = (ct >> 2) & 63;
    const int lhc = ct & 3;

    const int fq = lane >> 4;          // k-quarter 0..3

    float c_reg = 0.f;
    float hlast = 0.f;

    // prologue: x(0) partial into pbx[w4][0] (needs wlds -> barrier first)
    __syncthreads();
    if (isx) {
        f32x4 xa[4];
        #pragma unroll
        for (int m = 0; m < 4; ++m) xa[m] = (f32x4){0, 0, 0, 0};
        const unsigned short* xrow = xb + (size_t)(row0 + lrow) * 1024 + kq;
        #pragma unroll
        for (int f = 0; f < 32; ++f) {
            bf16x8 wf = *(const bf16x8*)&wlds[(f * 4 + fq) * WSTRIDE + lrow * 8];
            xa[f & 3] = __builtin_amdgcn_mfma_f32_16x16x32_bf16(
                *(const bf16x8*)(xrow + f * 32), wf, xa[f & 3], 0, 0, 0);
        }
        f32x4 xs = xa[0] + xa[1] + xa[2] + xa[3];
        #pragma unroll
        for (int r = 0; r < 4; ++r) pbx[w4][0][qr + r][lrow] = xs[r];
    }
    __syncthreads();

    for (int t = 0; t < TSTEPS; ++t) {
        if (isx) {
            // x(t+1) partial (off the h critical path)
            if (t + 1 < TSTEPS) {
                f32x4 xa[4];
                #pragma unroll
                for (int m = 0; m < 4; ++m) xa[m] = (f32x4){0, 0, 0, 0};
                const unsigned short* xrow = xb + ((size_t)(t + 1) << 16)
                                               + (size_t)(row0 + lrow) * 1024 + kq;
                #pragma unroll
                for (int f = 0; f < 32; ++f) {
                    bf16x8 wf = *(const bf16x8*)&wlds[(f * 4 + fq) * WSTRIDE + lrow * 8];
                    xa[f & 3] = __builtin_amdgcn_mfma_f32_16x16x32_bf16(
                        *(const bf16x8*)(xrow + f * 32), wf, xa[f & 3], 0, 0, 0);
                }
                f32x4 xs = xa[0] + xa[1] + xa[2] + xa[3];
                #pragma unroll
                for (int r = 0; r < 4; ++r) pbx[w4][(t + 1) & 1][qr + r][lrow] = xs[r];
            }
        } else {
            f32x4 acc[4];
            #pragma unroll
            for (int m = 0; m < 4; ++m) acc[m] = (f32x4){0, 0, 0, 0};
            if (t > 0) {
                // one-shot: issue all 32 h fragments (sc0sc1), wait once, sentinel-check, retry
                const unsigned short* hrow = hm + ((size_t)t << 16) + (size_t)(row0 + lrow) * 8;
                uint4 hq[32];
                int it = 0;
                for (;;) {
                    #pragma unroll
                    for (int f = 0; f < 32; ++f)
                        hq[f] = ld_b128_cp(hrow + (size_t)(f * 4 + fq) * 512);
                    asm volatile("s_waitcnt vmcnt(0)" ::: "memory");
                    __builtin_amdgcn_sched_barrier(0);   // rule #18
                    unsigned int bad = 0;
                    #pragma unroll
                    for (int f = 0; f < 32; ++f)
                        bad |= (hq[f].x == SENT) | (hq[f].y == SENT) |
                               (hq[f].z == SENT) | (hq[f].w == SENT);
                    if (__all(bad == 0) || ++it > (1 << 15)) break;
                }
                __builtin_amdgcn_sched_barrier(0);
                #pragma unroll
                for (int f = 0; f < 32; ++f) {
                    bf16x8 wf = *(const bf16x8*)&wlds[(128 + f * 4 + fq) * WSTRIDE + lrow * 8];
                    acc[f & 3] = __builtin_amdgcn_mfma_f32_16x16x32_bf16(
                        as_frag(hq[f]), wf, acc[f & 3], 0, 0, 0);
                }
            }
            f32x4 hs = acc[0] + acc[1] + acc[2] + acc[3];
            // same-wave transpose (in-order DS pipe, no barrier)
            #pragma unroll
            for (int r = 0; r < 4; ++r) pbh[w4][qr + r][lrow] = hs[r];
            asm volatile("s_waitcnt lgkmcnt(0)" ::: "memory");
            __builtin_amdgcn_sched_barrier(0);
            float4 xp = *(const float4*)&pbx[w4][t & 1][crow][chc << 2];
            float4 hp = *(const float4*)&pbh[w4][crow][chc << 2];
            float fpre = xp.x + hp.x + bb.x;
            float ipre = xp.y + hp.y + bb.y;
            float opre = xp.z + hp.z + bb.z;
            float gpre = xp.w + hp.w + bb.w;
            float fg = sigf(fpre);
            float ig = sigf(ipre);
            float og = sigf(opre);
            float gg = tanhfast(gpre);
            c_reg = fg * c_reg + ig * gg;
            float hh = og * tanhfast(c_reg);
            if (t == TSTEPS - 1) hlast = hh;

            // fire-and-forget publish: one 8B sc0sc1 store per 4 lanes
            unsigned int hb = f2b(hh);
            unsigned int p1 = __shfl_down(hb, 1);
            unsigned int p2 = __shfl_down(hb, 2);
            unsigned int p3 = __shfl_down(hb, 3);
            if (chc == 0) {
                u64 v = (u64)hb | ((u64)p1 << 16) | ((u64)p2 << 32) | ((u64)p3 << 48);
                unsigned short* dst = hm + ((size_t)(t + 1) << 16)
                                       + (size_t)(bid >> 1) * 512
                                       + (size_t)(row0 + crow) * 8 + ((bid & 1) << 2);
                asm volatile("global_store_dwordx2 %0, %1, off sc0 sc1" :: "v"(dst), "v"(v) : "memory");
            }
        }
        __syncthreads();   // pbx parity handoff (only barrier per step)
    }

    // c and h outputs
    if (!isx) {
        const int rg = row0 + crow;
        const int cg = (bid << 2) + chc;
        out[(size_t)rg * HD + cg] = c_reg;
        out[65536 + (size_t)rg * HD + cg] = hlast;
    }

    // final projection: last_out = h_256 @ V^T + V_b, blocks 0..63 (N=1024)
    if (bid < 64) {
        f32x4 acc[4];
        #pragma unroll
        for (int m = 0; m < 4; ++m) acc[m] = (f32x4){0, 0, 0, 0};
        const int ko2 = (wave << 7) + kq;                       // K=1024 split 8 x 128
        const unsigned short* vp = Vw + (size_t)(n0 + lrow) * HD + ko2;
        const unsigned short* hmt = hm + ((size_t)TSTEPS << 16);
        const int c8b = ko2 >> 3;
        uint4 pw[4], pv[4][4];
        #pragma unroll
        for (int j = 0; j < 4; ++j)
            pw[j] = ld_b128(vp + j * 32);
        int it = 0;
        for (;;) {
            #pragma unroll
            for (int j = 0; j < 4; ++j)
                #pragma unroll
                for (int m = 0; m < 4; ++m)
                    pv[j][m] = ld_b128_cp(hmt + (size_t)(c8b + j * 4) * 512 + (m * 16 + lrow) * 8);
            asm volatile("s_waitcnt vmcnt(0)" ::: "memory");
            __builtin_amdgcn_sched_barrier(0);   // rule #18
            unsigned int bad = 0;
            #pragma unroll
            for (int j = 0; j < 4; ++j)
                #pragma unroll
                for (int m = 0; m < 4; ++m)
                    bad |= (pv[j][m].x == SENT) | (pv[j][m].y == SENT) |
                           (pv[j][m].z == SENT) | (pv[j][m].w == SENT);
            if (__all(bad == 0) || ++it > (1 << 14)) break;
        }
        __builtin_amdgcn_sched_barrier(0);
        #pragma unroll
        for (int j = 0; j < 4; ++j)
            #pragma unroll
            for (int m = 0; m < 4; ++m)
                acc[m] = __builtin_amdgcn_mfma_f32_16x16x32_bf16(as_frag(pv[j][m]),
                                                                 as_frag(pw[j]), acc[m], 0, 0, 0);
        #pragma unroll
        for (int m = 0; m < 4; ++m)
            #pragma unroll
            for (int r = 0; r < 4; ++r)
                gxp[wave][m * 16 + qr + r][lrow] = acc[m][r];
        __syncthreads();
        if (tid >= 256) {
            float4 vb = *(const float4*)&Vbias[n0 + (lhc << 2)];
            float4 res = vb;
            #pragma unroll
            for (int w = 0; w < 8; ++w) {
                float4 s = *(const float4*)&gxp[w][ob][lhc << 2];
                res.x += s.x; res.y += s.y; res.z += s.z; res.w += s.w;
            }
            *(float4*)&out[131072 + (size_t)ob * 1024 + n0 + (lhc << 2)] = res;
        }
    }
}

extern "C" void kernel_launch(void* const* d_in, const int* in_sizes, int n_in,
                              void* d_out, int out_size, void* d_ws, size_t ws_size,
                              hipStream_t stream) {
    const float* x   = (const float*)d_in[0];
    const float* Wf  = (const float*)d_in[1];
    const float* bf_ = (const float*)d_in[2];
    const float* Wi  = (const float*)d_in[3];
    const float* bi_ = (const float*)d_in[4];
    const float* Wc  = (const float*)d_in[5];
    const float* bc_ = (const float*)d_in[6];
    const float* Wo  = (const float*)d_in[7];
    const float* bo_ = (const float*)d_in[8];
    const float* Vw  = (const float*)d_in[9];
    const float* Vb  = (const float*)d_in[10];

    char* ws = (char*)d_ws;
    unsigned short* Wr     = (unsigned short*)(ws + WOFF);
    unsigned short* Vbf    = (unsigned short*)(ws + VOFF);
    float*          bias_r = (float*)(ws + BOFF);
    unsigned short* hm     = (unsigned short*)(ws + HMOFF);
    unsigned short* xbb    = (unsigned short*)(ws + XBOFF);
    float*          outp   = (float*)d_out;

    cvt_x <<<8192, 256, 0, stream>>>(x, xbb);
    cvt_w <<<4096, 256, 0, stream>>>(Wf, Wi, Wo, Wc, bf_, bi_, bo_, bc_, Wr, bias_r);
    cvt_v <<<512, 256, 0, stream>>>(Vw, Vbf);
    init_sent<<<8192, 256, 0, stream>>>(hm + 65536);             // slots 1..256 = sentinel

    void* args[] = {&xbb, &Wr, &bias_r, &hm, &Vbf, (void*)&Vb, &outp};
    hipLaunchCooperativeKernel((const void*)lstm_core, dim3(256), dim3(512), args, 0, stream);
}